// Round 13
// baseline (1481.531 us; speedup 1.0000x reference)
//
#include <hip/hip_runtime.h>

constexpr int kB = 4, kN = 1024, kIn = 8, kD = 128, kH = 8, kNC = 64,
              kDK = 16, kFF = 512, kEnc = 6, kR = kB * kN;

__device__ __forceinline__ float wredsum(float v) {
  v += __shfl_xor(v, 1);  v += __shfl_xor(v, 2);  v += __shfl_xor(v, 4);
  v += __shfl_xor(v, 8);  v += __shfl_xor(v, 16); v += __shfl_xor(v, 32);
  return v;
}
__device__ __forceinline__ float wredmax(float v) {
  v = fmaxf(v, __shfl_xor(v, 1));  v = fmaxf(v, __shfl_xor(v, 2));
  v = fmaxf(v, __shfl_xor(v, 4));  v = fmaxf(v, __shfl_xor(v, 8));
  v = fmaxf(v, __shfl_xor(v, 16)); v = fmaxf(v, __shfl_xor(v, 32));
  return v;
}
__device__ __forceinline__ float red4(float v) {
  v += __shfl_xor(v, 1);  v += __shfl_xor(v, 2);
  return v;
}

// ---- prologue kernels ----

__global__ __launch_bounds__(256) void repack_qkv(
    const float* __restrict__ wq, const float* __restrict__ wk,
    const float* __restrict__ wv, float* __restrict__ out, int layers) {
  int i = blockIdx.x * 256 + threadIdx.x;
  if (i >= layers * kD * kD) return;
  int l = i / (kD * kD);
  int rem = i - l * kD * kD;
  int d = rem >> 7;
  int c = rem & 127;
  int src = ((l * kH + (c >> 4)) * kD + d) * kDK + (c & 15);
  out[(size_t)(l * 3 + 0) * 16384 + rem] = wq[src];
  out[(size_t)(l * 3 + 1) * 16384 + rem] = wk[src];
  out[(size_t)(l * 3 + 2) * 16384 + rem] = wv[src];
}

__global__ __launch_bounds__(256) void pack_mask(
    const int* __restrict__ edge_mask, const int* __restrict__ pad_mask,
    unsigned long long* __restrict__ bits_t) {
  int row = blockIdx.x;  // b*N + q
  int b = row / kN;
  int q = row % kN;
  int lane = threadIdx.x & 63;
  int wv = threadIdx.x >> 6;
  for (int c0 = wv; c0 < 16; c0 += 4) {
    int k = c0 * 64 + lane;
    int m = edge_mask[(size_t)row * kN + k] + pad_mask[b * kN + k];
    unsigned long long bal = __ballot(m > 0);
    if (lane == 0) bits_t[((size_t)b * 16 + c0) * kN + q] = bal;
  }
}

__global__ __launch_bounds__(256) void pack_pad(
    const int* __restrict__ pad_mask, unsigned long long* __restrict__ bits) {
  int b = blockIdx.x;
  int lane = threadIdx.x & 63;
  int wv = threadIdx.x >> 6;
  for (int c0 = wv; c0 < 16; c0 += 4) {
    int k = c0 * 64 + lane;
    unsigned long long bal = __ballot(pad_mask[b * kN + k] > 0);
    if (lane == 0) bits[b * 16 + c0] = bal;
  }
}

__global__ __launch_bounds__(256) void init_proj(
    const float* __restrict__ ni, const float* __restrict__ W,
    const float* __restrict__ bias, float* __restrict__ x) {
  int i = blockIdx.x * 256 + threadIdx.x;  // r*128 + c
  int r = i >> 7, c = i & 127;
  float acc = bias[c];
#pragma unroll
  for (int k = 0; k < kIn; k++) acc = fmaf(ni[r * kIn + k], W[k * kD + c], acc);
  x[i] = acc;
}

// ---- gtile3: fp32 GEMM, 16 rows x 128 cols/block, 2 rows x 4 CONSECUTIVE
// cols per thread. Both As and Ws inner reads are conflict-free b128
// (As rows padded +4 so half-wave addrs hit disjoint banks). K=128: whole W
// staged once (no loop syncs); K=512: 32-row double-buffered chunks.
template <int K, int LN, int RELU, int MODE>
__global__ __launch_bounds__(256) void gtile3(
    const float* __restrict__ A, const float* __restrict__ Wg,
    const float* __restrict__ gamma, const float* __restrict__ beta,
    const float* __restrict__ bias, const float* __restrict__ resid,
    float* __restrict__ O0, float* __restrict__ O1, float* __restrict__ O2,
    int Cfull) {
  constexpr bool FULLW = (K == 128);
  constexpr int NC = K / 32;
  __shared__ float As[16][K + 4];
  __shared__ float Ws[FULLW ? 4 : 2][32][128];
  int r0 = blockIdx.x * 16;
  int y = blockIdx.y;
  const float* Wb;
  int wstride;
  if constexpr (MODE == 2) { Wb = Wg + (size_t)y * K * 128; wstride = 128; }
  else { Wb = Wg + (size_t)y * 128; wstride = Cfull; }

  // ---- stage A (opt fused LN) ----
  if constexpr (LN) {
    static_assert(K == 128, "LN requires K==128");
    int w = threadIdx.x >> 6, lane = threadIdx.x & 63;
#pragma unroll
    for (int i = 0; i < 4; i++) {
      int rr = w * 4 + i;
      const float* xr = A + (size_t)(r0 + rr) * 128;
      float2 v = *(const float2*)(xr + lane * 2);
      float mean = wredsum(v.x + v.y) * (1.0f / 128.f);
      float dx = v.x - mean, dy = v.y - mean;
      float var = wredsum(dx * dx + dy * dy) * (1.0f / 128.f);
      float rstd = rsqrtf(var + 1e-5f);
      int c = lane * 2;
      As[rr][c] = dx * rstd * gamma[c] + beta[c];
      As[rr][c + 1] = dy * rstd * gamma[c + 1] + beta[c + 1];
    }
  } else {
    constexpr int NF4 = K / 4;
#pragma unroll
    for (int f = threadIdx.x; f < 16 * NF4; f += 256) {
      int row = f / NF4, c4i = f % NF4;
      *(float4*)&As[row][c4i * 4] =
          *(const float4*)(A + (size_t)(r0 + row) * K + c4i * 4);
    }
  }

  int c4 = (threadIdx.x & 31) * 4;   // 4 consecutive cols
  int rg = threadIdx.x >> 5;         // rows rg*2, rg*2+1
  float acc[2][4] = {};

  if constexpr (FULLW) {
    // stage whole 128x128 W: 4096 float4, 16 per thread, coalesced
#pragma unroll
    for (int i = 0; i < 16; i++) {
      int idx = threadIdx.x + i * 256;
      int row = idx >> 5, cc = idx & 31;
      *(float4*)&Ws[row >> 5][row & 31][cc * 4] =
          *(const float4*)(Wb + (size_t)row * wstride + cc * 4);
    }
    __syncthreads();
#pragma unroll
    for (int kc = 0; kc < 4; kc++) {
#pragma unroll
      for (int k4 = 0; k4 < 8; k4++) {
        float4 a0 = *(const float4*)&As[rg * 2][kc * 32 + k4 * 4];
        float4 a1 = *(const float4*)&As[rg * 2 + 1][kc * 32 + k4 * 4];
#pragma unroll
        for (int m = 0; m < 4; m++) {
          float4 wv = *(const float4*)&Ws[kc][k4 * 4 + m][c4];
          float av0 = ((const float*)&a0)[m];
          float av1 = ((const float*)&a1)[m];
          acc[0][0] = fmaf(av0, wv.x, acc[0][0]);
          acc[0][1] = fmaf(av0, wv.y, acc[0][1]);
          acc[0][2] = fmaf(av0, wv.z, acc[0][2]);
          acc[0][3] = fmaf(av0, wv.w, acc[0][3]);
          acc[1][0] = fmaf(av1, wv.x, acc[1][0]);
          acc[1][1] = fmaf(av1, wv.y, acc[1][1]);
          acc[1][2] = fmaf(av1, wv.z, acc[1][2]);
          acc[1][3] = fmaf(av1, wv.w, acc[1][3]);
        }
      }
    }
  } else {
    // double-buffered 32-row chunks (lane-linear conflict-free staging)
    int wrow = threadIdx.x >> 5;
    int wc4 = threadIdx.x & 31;
    float4 wreg[4];
    auto loadW = [&](int kc) {
      const float* Wr = Wb + (size_t)(kc * 32 + wrow) * wstride + wc4 * 4;
#pragma unroll
      for (int j = 0; j < 4; j++)
        wreg[j] = *(const float4*)(Wr + (size_t)8 * j * wstride);
    };
    auto writeW = [&](int buf) {
#pragma unroll
      for (int j = 0; j < 4; j++)
        *(float4*)&Ws[buf][wrow + 8 * j][wc4 * 4] = wreg[j];
    };
    loadW(0);
    writeW(0);
    for (int kc = 0; kc < NC; kc++) {
      if (kc + 1 < NC) loadW(kc + 1);
      __syncthreads();
#pragma unroll
      for (int k4 = 0; k4 < 8; k4++) {
        float4 a0 = *(const float4*)&As[rg * 2][kc * 32 + k4 * 4];
        float4 a1 = *(const float4*)&As[rg * 2 + 1][kc * 32 + k4 * 4];
#pragma unroll
        for (int m = 0; m < 4; m++) {
          float4 wv = *(const float4*)&Ws[kc & 1][k4 * 4 + m][c4];
          float av0 = ((const float*)&a0)[m];
          float av1 = ((const float*)&a1)[m];
          acc[0][0] = fmaf(av0, wv.x, acc[0][0]);
          acc[0][1] = fmaf(av0, wv.y, acc[0][1]);
          acc[0][2] = fmaf(av0, wv.z, acc[0][2]);
          acc[0][3] = fmaf(av0, wv.w, acc[0][3]);
          acc[1][0] = fmaf(av1, wv.x, acc[1][0]);
          acc[1][1] = fmaf(av1, wv.y, acc[1][1]);
          acc[1][2] = fmaf(av1, wv.z, acc[1][2]);
          acc[1][3] = fmaf(av1, wv.w, acc[1][3]);
        }
      }
      if (kc + 1 < NC) writeW((kc + 1) & 1);
    }
  }

  // ---- epilogue ----
#pragma unroll
  for (int rr = 0; rr < 2; rr++) {
    int r = r0 + rg * 2 + rr;
    if constexpr (MODE == 2) {
#pragma unroll
      for (int j = 0; j < 4; j++) {
        int c = c4 + j;
        float v = acc[rr][j];
        int hh = c >> 4, e = c & 15;
        int bb = r >> 10, n = r & 1023;
        float* P = (y == 0) ? O0 : (y == 1) ? O1 : O2;
        P[(((size_t)(bb * kH + hh)) * kN + n) * kDK + e] = v;
      }
    } else {
      int colg = y * 128 + c4;
      float4 v = make_float4(acc[rr][0], acc[rr][1], acc[rr][2], acc[rr][3]);
      if (bias) {
        float4 bv = *(const float4*)(bias + colg);
        v.x += bv.x; v.y += bv.y; v.z += bv.z; v.w += bv.w;
      }
      if (resid) {
        float4 rv = *(const float4*)(resid + (size_t)r * Cfull + colg);
        v.x += rv.x; v.y += rv.y; v.z += rv.z; v.w += rv.w;
      }
      if (RELU) {
        v.x = fmaxf(v.x, 0.f); v.y = fmaxf(v.y, 0.f);
        v.z = fmaxf(v.z, 0.f); v.w = fmaxf(v.w, 0.f);
      }
      *(float4*)(O0 + (size_t)r * Cfull + colg) = v;
    }
  }
}

// ---- flash attention v3: 128 q per block (2 per lane), 8 k-split waves ----
__global__ __launch_bounds__(512) void attn_flash3(
    const float* __restrict__ Q, const float* __restrict__ K,
    const float* __restrict__ V, const unsigned long long* __restrict__ bits_t,
    float* __restrict__ Hd) {
  __shared__ float Ks[8][64][20];
  __shared__ float Vs[8][64][20];
  int bh = blockIdx.x, qt = blockIdx.y;
  int b = bh >> 3, h = bh & 7;
  int w = threadIdx.x >> 6, lane = threadIdx.x & 63;
  int q0 = qt * 128 + lane, q1 = q0 + 64;
  const float4* qp0 = (const float4*)(Q + ((size_t)bh * kN + q0) * kDK);
  const float4* qp1 = (const float4*)(Q + ((size_t)bh * kN + q1) * kDK);
  float4 qa0 = qp0[0], qa1 = qp0[1], qa2 = qp0[2], qa3 = qp0[3];
  float4 qb0 = qp1[0], qb1 = qp1[1], qb2 = qp1[2], qb3 = qp1[3];
  const float* Kb = K + (size_t)bh * kN * kDK;
  const float* Vb = V + (size_t)bh * kN * kDK;
  float mx0 = -3.0e38f, l0 = 0.f, mx1 = -3.0e38f, l1 = 0.f;
  float acc0[16], acc1[16];
#pragma unroll
  for (int e = 0; e < 16; e++) { acc0[e] = 0.f; acc1[e] = 0.f; }
  for (int t = 0; t < 2; t++) {
    int kk = w * 128 + t * 64 + lane;
    const float4* kp = (const float4*)(Kb + (size_t)kk * kDK);
    float4 ka = kp[0], kb2 = kp[1], kc = kp[2], kd = kp[3];
    const float4* vp = (const float4*)(Vb + (size_t)kk * kDK);
    float4 va = vp[0], vb = vp[1], vc = vp[2], vd = vp[3];
    unsigned long long mb0 = bits_t[((size_t)b * 16 + w * 2 + t) * kN + q0];
    unsigned long long mb1 = bits_t[((size_t)b * 16 + w * 2 + t) * kN + q1];
    ((float4*)&Ks[w][lane][0])[0] = ka;  ((float4*)&Ks[w][lane][0])[1] = kb2;
    ((float4*)&Ks[w][lane][0])[2] = kc;  ((float4*)&Ks[w][lane][0])[3] = kd;
    ((float4*)&Vs[w][lane][0])[0] = va;  ((float4*)&Vs[w][lane][0])[1] = vb;
    ((float4*)&Vs[w][lane][0])[2] = vc;  ((float4*)&Vs[w][lane][0])[3] = vd;
#pragma unroll 2
    for (int k2 = 0; k2 < 64; k2++) {
      const float4* kr = (const float4*)&Ks[w][k2][0];
      float4 k0 = kr[0], k1 = kr[1], k2v = kr[2], k3 = kr[3];
      float s0 = qa0.x * k0.x + qa0.y * k0.y + qa0.z * k0.z + qa0.w * k0.w
               + qa1.x * k1.x + qa1.y * k1.y + qa1.z * k1.z + qa1.w * k1.w
               + qa2.x * k2v.x + qa2.y * k2v.y + qa2.z * k2v.z + qa2.w * k2v.w
               + qa3.x * k3.x + qa3.y * k3.y + qa3.z * k3.z + qa3.w * k3.w;
      float s1 = qb0.x * k0.x + qb0.y * k0.y + qb0.z * k0.z + qb0.w * k0.w
               + qb1.x * k1.x + qb1.y * k1.y + qb1.z * k1.z + qb1.w * k1.w
               + qb2.x * k2v.x + qb2.y * k2v.y + qb2.z * k2v.z + qb2.w * k2v.w
               + qb3.x * k3.x + qb3.y * k3.y + qb3.z * k3.z + qb3.w * k3.w;
      s0 *= 0.25f; s1 *= 0.25f;
      if ((mb0 >> k2) & 1ull) s0 = -1e8f;
      if ((mb1 >> k2) & 1ull) s1 = -1e8f;
      float d0 = s0 - mx0;
      if (d0 > 8.f) {
        float sc = __expf(-d0);
        l0 *= sc;
#pragma unroll
        for (int e = 0; e < 16; e++) acc0[e] *= sc;
        mx0 = s0; d0 = 0.f;
      }
      float p0 = __expf(d0);
      l0 += p0;
      float d1 = s1 - mx1;
      if (d1 > 8.f) {
        float sc = __expf(-d1);
        l1 *= sc;
#pragma unroll
        for (int e = 0; e < 16; e++) acc1[e] *= sc;
        mx1 = s1; d1 = 0.f;
      }
      float p1 = __expf(d1);
      l1 += p1;
      const float4* vr = (const float4*)&Vs[w][k2][0];
      float4 v0 = vr[0], v1 = vr[1], v2 = vr[2], v3 = vr[3];
      acc0[0] = fmaf(p0, v0.x, acc0[0]);   acc0[1] = fmaf(p0, v0.y, acc0[1]);
      acc0[2] = fmaf(p0, v0.z, acc0[2]);   acc0[3] = fmaf(p0, v0.w, acc0[3]);
      acc0[4] = fmaf(p0, v1.x, acc0[4]);   acc0[5] = fmaf(p0, v1.y, acc0[5]);
      acc0[6] = fmaf(p0, v1.z, acc0[6]);   acc0[7] = fmaf(p0, v1.w, acc0[7]);
      acc0[8] = fmaf(p0, v2.x, acc0[8]);   acc0[9] = fmaf(p0, v2.y, acc0[9]);
      acc0[10] = fmaf(p0, v2.z, acc0[10]); acc0[11] = fmaf(p0, v2.w, acc0[11]);
      acc0[12] = fmaf(p0, v3.x, acc0[12]); acc0[13] = fmaf(p0, v3.y, acc0[13]);
      acc0[14] = fmaf(p0, v3.z, acc0[14]); acc0[15] = fmaf(p0, v3.w, acc0[15]);
      acc1[0] = fmaf(p1, v0.x, acc1[0]);   acc1[1] = fmaf(p1, v0.y, acc1[1]);
      acc1[2] = fmaf(p1, v0.z, acc1[2]);   acc1[3] = fmaf(p1, v0.w, acc1[3]);
      acc1[4] = fmaf(p1, v1.x, acc1[4]);   acc1[5] = fmaf(p1, v1.y, acc1[5]);
      acc1[6] = fmaf(p1, v1.z, acc1[6]);   acc1[7] = fmaf(p1, v1.w, acc1[7]);
      acc1[8] = fmaf(p1, v2.x, acc1[8]);   acc1[9] = fmaf(p1, v2.y, acc1[9]);
      acc1[10] = fmaf(p1, v2.z, acc1[10]); acc1[11] = fmaf(p1, v2.w, acc1[11]);
      acc1[12] = fmaf(p1, v3.x, acc1[12]); acc1[13] = fmaf(p1, v3.y, acc1[13]);
      acc1[14] = fmaf(p1, v3.z, acc1[14]); acc1[15] = fmaf(p1, v3.w, acc1[15]);
    }
  }
  __syncthreads();
  float* M0 = &Ks[w][lane][0];
  float* M1 = &Vs[w][lane][0];
#pragma unroll
  for (int e = 0; e < 16; e++) { M0[e] = acc0[e]; M1[e] = acc1[e]; }
  M0[16] = mx0; M0[17] = l0;
  M1[16] = mx1; M1[17] = l1;
  __syncthreads();
#pragma unroll
  for (int half = 0; half < 2; half++) {
    const float* M = half ? &Vs[0][0][0] : &Ks[0][0][0];
    float mv[8];
#pragma unroll
    for (int p = 0; p < 8; p++) mv[p] = M[(p * 64 + lane) * 20 + 16];
    float mstar = mv[0];
#pragma unroll
    for (int p = 1; p < 8; p++) mstar = fmaxf(mstar, mv[p]);
    float f[8];
    float L = 0.f;
#pragma unroll
    for (int p = 0; p < 8; p++) {
      f[p] = __expf(mv[p] - mstar);
      L += f[p] * M[(p * 64 + lane) * 20 + 17];
    }
    float invL = 1.0f / L;
    float o[2];
#pragma unroll
    for (int e = 0; e < 2; e++) {
      int ei = w * 2 + e;
      float a = 0.f;
#pragma unroll
      for (int p = 0; p < 8; p++) a += f[p] * M[(p * 64 + lane) * 20 + ei];
      o[e] = a * invL;
    }
    int q = qt * 128 + half * 64 + lane;
    *(float2*)(Hd + ((size_t)(b * kN + q)) * kD + h * kDK + w * 2) =
        make_float2(o[0], o[1]);
  }
}

// ==== decoder (algebraic: K/V never materialized) ====

__global__ __launch_bounds__(256) void dec_prep(
    const float* __restrict__ enh, const int* __restrict__ tgt_idx,
    const int* __restrict__ cur_idx, const int* __restrict__ cen_idx,
    const float* __restrict__ Wq,
    const float* __restrict__ ln1_g, const float* __restrict__ ln1_b,
    const float* __restrict__ dec_wk,
    float* __restrict__ out_curf, float* __restrict__ out_cenf,
    float* __restrict__ tgtf_ws, float* __restrict__ qk_ws) {
  __shared__ float tgtf_s[128], tgtn[128], qd[128];
  int b = blockIdx.x, t = threadIdx.x;
  int lane = t & 63, w = t >> 6;
  int ti = tgt_idx[b], cui = cur_idx[b];
  if (t < 128) {
    float tf = enh[((size_t)b * kN + ti) * kD + t];
    tgtf_s[t] = tf;
    tgtf_ws[b * kD + t] = tf;
    out_curf[b * kD + t] = enh[((size_t)b * kN + cui) * kD + t];
  }
  for (int i = t; i < kNC * kD; i += 256) {
    int c = i >> 7, e = i & 127;
    out_cenf[((size_t)b * kNC + c) * kD + e] =
        enh[((size_t)b * kN + cen_idx[b * kNC + c]) * kD + e];
  }
  __syncthreads();
  if (w == 0) {
    float vx = tgtf_s[lane * 2], vy = tgtf_s[lane * 2 + 1];
    float mean = wredsum(vx + vy) * (1.0f / 128.f);
    float dx = vx - mean, dy = vy - mean;
    float var = wredsum(dx * dx + dy * dy) * (1.0f / 128.f);
    float rstd = rsqrtf(var + 1e-5f);
    tgtn[lane * 2] = dx * rstd * ln1_g[lane * 2] + ln1_b[lane * 2];
    tgtn[lane * 2 + 1] = dy * rstd * ln1_g[lane * 2 + 1] + ln1_b[lane * 2 + 1];
  }
  __syncthreads();
  if (t < 128) {
    float a = 0.f;
#pragma unroll 8
    for (int k = 0; k < 128; k++) a = fmaf(tgtn[k], Wq[k * 128 + t], a);
    qd[t] = a;
  }
  __syncthreads();
  int h = t >> 5, d0 = (t & 31) * 4;
#pragma unroll
  for (int j = 0; j < 4; j++) {
    int d = d0 + j;
    const float4* wp = (const float4*)(dec_wk + (((size_t)h * 128 + d) << 4));
    float a = 0.f;
#pragma unroll
    for (int r = 0; r < 4; r++) {
      float4 wv = wp[r];
      a += wv.x * qd[h * 16 + r * 4] + wv.y * qd[h * 16 + r * 4 + 1] +
           wv.z * qd[h * 16 + r * 4 + 2] + wv.w * qd[h * 16 + r * 4 + 3];
    }
    qk_ws[b * 1024 + h * 128 + d] = 0.25f * a;
  }
}

__global__ __launch_bounds__(256) void dec_score(
    const float* __restrict__ enh, const float* __restrict__ ln_g,
    const float* __restrict__ ln_b, const float* __restrict__ qk_ws,
    const unsigned long long* __restrict__ padbits,
    float* __restrict__ ln_ws, float* __restrict__ scores) {
  __shared__ float qs[8][128];
  int b = blockIdx.x, nt = blockIdx.y, t = threadIdx.x;
  for (int i = t; i < 1024; i += 256) ((float*)qs)[i] = qk_ws[b * 1024 + i];
  __syncthreads();
  int w = t >> 6, lane = t & 63, ri = lane >> 2, q4 = lane & 3;
  int n = nt * 64 + w * 16 + ri;
  const float* row = enh + ((size_t)b * kN + n) * kD;
  float4 xv[8];
#pragma unroll
  for (int j = 0; j < 8; j++) xv[j] = *(const float4*)(row + j * 16 + q4 * 4);
  float s1 = 0.f;
#pragma unroll
  for (int j = 0; j < 8; j++) s1 += xv[j].x + xv[j].y + xv[j].z + xv[j].w;
  s1 = red4(s1);
  float mean = s1 * (1.0f / 128.f);
  float s2 = 0.f;
#pragma unroll
  for (int j = 0; j < 8; j++) {
    xv[j].x -= mean; xv[j].y -= mean; xv[j].z -= mean; xv[j].w -= mean;
    s2 += xv[j].x * xv[j].x + xv[j].y * xv[j].y + xv[j].z * xv[j].z +
          xv[j].w * xv[j].w;
  }
  s2 = red4(s2);
  float rstd = rsqrtf(s2 * (1.0f / 128.f) + 1e-5f);
#pragma unroll
  for (int j = 0; j < 8; j++) {
    int d0 = j * 16 + q4 * 4;
    float4 g = *(const float4*)(ln_g + d0);
    float4 be = *(const float4*)(ln_b + d0);
    xv[j].x = xv[j].x * rstd * g.x + be.x;
    xv[j].y = xv[j].y * rstd * g.y + be.y;
    xv[j].z = xv[j].z * rstd * g.z + be.z;
    xv[j].w = xv[j].w * rstd * g.w + be.w;
    *(float4*)(ln_ws + ((size_t)b * kN + n) * kD + d0) = xv[j];
  }
  bool mk = (padbits[b * 16 + (n >> 6)] >> (n & 63)) & 1ull;
#pragma unroll
  for (int h = 0; h < 8; h++) {
    float p = 0.f;
#pragma unroll
    for (int j = 0; j < 8; j++) {
      float4 qv = *(const float4*)&qs[h][j * 16 + q4 * 4];
      p += xv[j].x * qv.x + xv[j].y * qv.y + xv[j].z * qv.z + xv[j].w * qv.w;
    }
    p = red4(p);
    if (q4 == 0) scores[((size_t)b * 8 + h) * 1024 + n] = mk ? -1e8f : p;
  }
}

__global__ __launch_bounds__(256) void dec_softmax(
    const float* __restrict__ scores, float* __restrict__ ml) {
  int b = blockIdx.x, t = threadIdx.x, w = t >> 6, lane = t & 63;
  for (int hi = 0; hi < 2; hi++) {
    int h = w + hi * 4;
    const float* sr = scores + ((size_t)b * 8 + h) * 1024;
    float v[16];
    float m = -3.0e38f;
#pragma unroll
    for (int i = 0; i < 16; i++) { v[i] = sr[i * 64 + lane]; m = fmaxf(m, v[i]); }
    m = wredmax(m);
    float l = 0.f;
#pragma unroll
    for (int i = 0; i < 16; i++) l += __expf(v[i] - m);
    l = wredsum(l);
    if (lane == 0) { ml[(b * 8 + h) * 2] = m; ml[(b * 8 + h) * 2 + 1] = l; }
  }
}

__global__ __launch_bounds__(256) void dec_attnsum(
    const float* __restrict__ ln_ws, const float* __restrict__ scores,
    const float* __restrict__ ml, float* __restrict__ partial) {
  __shared__ float lns[64][128];
  __shared__ float ps[8][64];
  int b = blockIdx.x, nt = blockIdx.y, t = threadIdx.x;
  for (int i = t; i < 64 * 32; i += 256) {
    int nn = i >> 5, c4 = i & 31;
    *(float4*)&lns[nn][c4 * 4] =
        *(const float4*)(ln_ws + ((size_t)b * kN + nt * 64 + nn) * kD + c4 * 4);
  }
  for (int i = t; i < 512; i += 256) {
    int h = i >> 6, nn = i & 63;
    float m = ml[(b * 8 + h) * 2], l = ml[(b * 8 + h) * 2 + 1];
    ps[h][nn] =
        __expf(scores[((size_t)b * 8 + h) * 1024 + nt * 64 + nn] - m) / l;
  }
  __syncthreads();
  int h = t >> 5, d0 = (t & 31) * 4;
  float4 acc = make_float4(0.f, 0.f, 0.f, 0.f);
  for (int nn = 0; nn < 64; nn++) {
    float p = ps[h][nn];
    float4 lv = *(const float4*)&lns[nn][d0];
    acc.x = fmaf(p, lv.x, acc.x); acc.y = fmaf(p, lv.y, acc.y);
    acc.z = fmaf(p, lv.z, acc.z); acc.w = fmaf(p, lv.w, acc.w);
  }
  *(float4*)(partial + ((size_t)(b * 16 + nt) * 8 + h) * 128 + d0) = acc;
}

// dec_tail: 1024 threads, parallel-k matvecs via LDS partial reduce
__global__ __launch_bounds__(1024) void dec_tail(
    const float* __restrict__ partial, const float* __restrict__ dec_wv,
    const float* __restrict__ dwo, const float* __restrict__ tgtf_ws,
    const float* __restrict__ cenf_g, const float* __restrict__ Kp,
    const int* __restrict__ cen_idx, const int* __restrict__ center_mask,
    const float* __restrict__ ln2_g, const float* __restrict__ ln2_b,
    const float* __restrict__ w1, const float* __restrict__ b1,
    const float* __restrict__ w2, const float* __restrict__ b2,
    const float* __restrict__ tgt_W, const float* __restrict__ tgt_b,
    const float* __restrict__ ptr_wq,
    float* __restrict__ out_selidx, float* __restrict__ out_selfeat,
    float* __restrict__ out_logp) {
  __shared__ float wsum[8][132];
  __shared__ float red[8][132];
  __shared__ float red2[2][520];
  __shared__ float red16[16][68];
  __shared__ float tgtf[128], hdd[128], dechs[128], decfs[128], dects[512],
                   embs[128], qps[128];
  __shared__ int bi_s;
  int b = blockIdx.x, t = threadIdx.x;
  int c = t & 127, p = t >> 7;
  int lane = t & 63, w = t >> 6;

  {
    float a = 0.f;
#pragma unroll
    for (int tt = 0; tt < 16; tt++)
      a += partial[((size_t)(b * 16 + tt) * 8 + p) * 128 + c];
    wsum[p][c] = a;
    if (t < 128) tgtf[t] = tgtf_ws[b * kD + t];
  }
  __syncthreads();

  {
    int h = c >> 4, e = c & 15;
    float a = 0.f;
#pragma unroll
    for (int i = 0; i < 16; i++) {
      int d = p * 16 + i;
      a = fmaf(wsum[h][d], dec_wv[((size_t)h * 128 + d) * 16 + e], a);
    }
    red[p][c] = a;
  }
  __syncthreads();
  if (t < 128) {
    float a = 0.f;
#pragma unroll
    for (int q = 0; q < 8; q++) a += red[q][t];
    hdd[t] = a;
  }
  __syncthreads();

  {
    float a = 0.f;
#pragma unroll
    for (int i = 0; i < 16; i++) {
      int k = p * 16 + i;
      a = fmaf(hdd[k], dwo[k * 128 + c], a);
    }
    red[p][c] = a;
  }
  __syncthreads();
  if (t < 128) {
    float a = 0.f;
#pragma unroll
    for (int q = 0; q < 8; q++) a += red[q][t];
    dechs[t] = a + tgtf[t];
  }
  __syncthreads();

  if (w == 0) {
    float vx = dechs[lane * 2], vy = dechs[lane * 2 + 1];
    float mean = wredsum(vx + vy) * (1.0f / 128.f);
    float dx = vx - mean, dy = vy - mean;
    float var = wredsum(dx * dx + dy * dy) * (1.0f / 128.f);
    float rstd = rsqrtf(var + 1e-5f);
    decfs[lane * 2] = dx * rstd * ln2_g[lane * 2] + ln2_b[lane * 2];
    decfs[lane * 2 + 1] = dy * rstd * ln2_g[lane * 2 + 1] + ln2_b[lane * 2 + 1];
  }
  __syncthreads();

  {
    int c5 = t & 511, p2 = t >> 9;
    float a = 0.f;
#pragma unroll 8
    for (int i = 0; i < 64; i++) {
      int k = p2 * 64 + i;
      a = fmaf(decfs[k], w1[k * 512 + c5], a);
    }
    red2[p2][c5] = a;
  }
  __syncthreads();
  if (t < 512) dects[t] = fmaxf(red2[0][t] + red2[1][t] + b1[t], 0.f);
  __syncthreads();

  {
    float a = 0.f;
#pragma unroll 8
    for (int i = 0; i < 64; i++) {
      int k = p * 64 + i;
      a = fmaf(dects[k], w2[k * 128 + c], a);
    }
    red[p][c] = a;
  }
  __syncthreads();
  if (t < 128) {
    float a = 0.f;
#pragma unroll
    for (int q = 0; q < 8; q++) a += red[q][t];
    decfs[t] = a + b2[t] + dechs[t];
  }
  __syncthreads();

  {
    float a = 0.f;
#pragma unroll
    for (int i = 0; i < 32; i++) {
      int k = p * 32 + i;
      float vkk = (k < 128) ? decfs[k] : tgtf[k - 128];
      a = fmaf(vkk, tgt_W[k * 128 + c], a);
    }
    red[p][c] = a;
  }
  __syncthreads();
  if (t < 128) {
    float a = 0.f;
#pragma unroll
    for (int q = 0; q < 8; q++) a += red[q][t];
    embs[t] = a + tgt_b[t];
  }
  __syncthreads();

  {
    float a = 0.f;
#pragma unroll
    for (int i = 0; i < 16; i++) {
      int k = p * 16 + i;
      a = fmaf(embs[k], ptr_wq[k * 128 + c], a);
    }
    red[p][c] = a;
  }
  __syncthreads();
  if (t < 128) {
    float a = 0.f;
#pragma unroll
    for (int q = 0; q < 8; q++) a += red[q][t];
    qps[t] = a;
  }
  __syncthreads();

  {
    int cen = t & 63, p16 = t >> 6;
    float a = 0.f;
#pragma unroll
    for (int i = 0; i < 8; i++) {
      int k = p16 * 8 + i;
      a = fmaf(qps[k], Kp[((size_t)(b * kNC + cen)) * kD + k], a);
    }
    red16[p16][cen] = a;
  }
  __syncthreads();
  if (w == 0) {
    float u = 0.f;
#pragma unroll
    for (int q = 0; q < 16; q++) u += red16[q][lane];
    u *= 0.08838834764831845f;
    u = 10.0f * tanhf(u);
    if (center_mask[b * kNC + lane] == 1) u = -1e8f;
    float m = wredmax(u);
    float ex = __expf(u - m);
    float sum = wredsum(ex);
    out_logp[b * kNC + lane] = u - m - logf(sum);
    float bm = u; int bi = lane;
#pragma unroll
    for (int o = 32; o; o >>= 1) {
      float om = __shfl_xor(bm, o);
      int oi = __shfl_xor(bi, o);
      if (om > bm || (om == bm && oi < bi)) { bm = om; bi = oi; }
    }
    if (lane == 0) {
      out_selidx[b] = (float)cen_idx[b * kNC + bi];
      bi_s = bi;
    }
  }
  __syncthreads();
  if (t < 128)
    out_selfeat[b * kD + t] = cenf_g[((size_t)(b * kNC + bi_s)) * kD + t];
}

// ---- host ----

extern "C" void kernel_launch(void* const* d_in, const int* in_sizes, int n_in,
                              void* d_out, int out_size, void* d_ws,
                              size_t ws_size, hipStream_t stream) {
  (void)in_sizes; (void)n_in; (void)out_size; (void)ws_size;
  const float* node_inputs = (const float*)d_in[0];
  const int* pad_mask = (const int*)d_in[1];
  const int* edge_mask = (const int*)d_in[2];
  const int* center_mask = (const int*)d_in[3];
  const int* center_index = (const int*)d_in[4];
  const int* target_index = (const int*)d_in[5];
  const int* current_index = (const int*)d_in[6];
  const float* init_W = (const float*)d_in[8];
  const float* init_b = (const float*)d_in[9];
  const float* enc_wq = (const float*)d_in[10];
  const float* enc_wk = (const float*)d_in[11];
  const float* enc_wv = (const float*)d_in[12];
  const float* enc_wo = (const float*)d_in[13];
  const float* enc_ln1_g = (const float*)d_in[14];
  const float* enc_ln1_b = (const float*)d_in[15];
  const float* enc_w1 = (const float*)d_in[16];
  const float* enc_b1 = (const float*)d_in[17];
  const float* enc_w2 = (const float*)d_in[18];
  const float* enc_b2 = (const float*)d_in[19];
  const float* enc_ln2_g = (const float*)d_in[20];
  const float* enc_ln2_b = (const float*)d_in[21];
  const float* dec_wq = (const float*)d_in[22];
  const float* dec_wk = (const float*)d_in[23];
  const float* dec_wv = (const float*)d_in[24];
  const float* dec_wo = (const float*)d_in[25];
  const float* dec_ln1_g = (const float*)d_in[26];
  const float* dec_ln1_b = (const float*)d_in[27];
  const float* dec_w1 = (const float*)d_in[28];
  const float* dec_b1 = (const float*)d_in[29];
  const float* dec_w2 = (const float*)d_in[30];
  const float* dec_b2 = (const float*)d_in[31];
  const float* dec_ln2_g = (const float*)d_in[32];
  const float* dec_ln2_b = (const float*)d_in[33];
  const float* tgt_W = (const float*)d_in[34];
  const float* tgt_b = (const float*)d_in[35];
  const float* ptr_wq = (const float*)d_in[36];
  const float* ptr_wk = (const float*)d_in[37];

  float* out_enh = (float*)d_out;
  float* out_curf = out_enh + kB * kN * kD;
  float* out_selidx = out_curf + kB * kD;
  float* out_selfeat = out_selidx + kB;
  float* out_logp = out_selfeat + kB * kD;
  float* out_cenf = out_logp + kB * kNC;

  char* wsp = (char*)d_ws;
  size_t off = 0;
  auto alloc = [&](size_t n) {
    char* p = wsp + off;
    off = (off + n + 255) & ~(size_t)255;
    return p;
  };
  float* x   = (float*)alloc(kR * kD * 4);
  float* h2  = (float*)alloc(kR * kD * 4);
  float* Qb  = (float*)alloc(kR * kD * 4);
  float* Kb  = (float*)alloc(kR * kD * 4);
  float* Vb  = (float*)alloc(kR * kD * 4);
  float* Hd  = (float*)alloc(kR * kD * 4);
  float* tb  = (float*)alloc(kR * kFF * 4);
  unsigned long long* bits_t  = (unsigned long long*)alloc(kR * 16 * 8);
  unsigned long long* padbits = (unsigned long long*)alloc(kB * 16 * 8);
  float* ewqkv = (float*)alloc(kEnc * 3 * kD * kD * 4);
  float* dqkvW = (float*)alloc(3 * kD * kD * 4);
  float* ln_ws = (float*)alloc(kR * kD * 4);
  float* scores_ws = (float*)alloc(kB * kH * kN * 4);
  float* ml_ws = (float*)alloc(kB * kH * 2 * 4);
  float* partial_ws = (float*)alloc(kB * 16 * kH * kD * 4);
  float* qk_ws = (float*)alloc(kB * kH * kD * 4);
  float* tgtf_ws = (float*)alloc(kB * kD * 4);
  float* Kp_ws = (float*)alloc(kB * kNC * kD * 4);

  // prologue
  repack_qkv<<<(kEnc * kD * kD + 255) / 256, 256, 0, stream>>>(
      enc_wq, enc_wk, enc_wv, ewqkv, kEnc);
  repack_qkv<<<(kD * kD + 255) / 256, 256, 0, stream>>>(
      dec_wq, dec_wk, dec_wv, dqkvW, 1);
  pack_mask<<<kB * kN, 256, 0, stream>>>(edge_mask, pad_mask, bits_t);
  pack_pad<<<kB, 256, 0, stream>>>(pad_mask, padbits);
  init_proj<<<kR * kD / 256, 256, 0, stream>>>(node_inputs, init_W, init_b, x);

  // encoder
  for (int l = 0; l < kEnc; l++) {
    const float* wo_l = enc_wo + (size_t)l * kH * kDK * kD;
    gtile3<128, 1, 0, 2><<<dim3(kR / 16, 3), 256, 0, stream>>>(
        x, ewqkv + (size_t)l * 3 * kD * kD, enc_ln1_g + l * kD,
        enc_ln1_b + l * kD, nullptr, nullptr, Qb, Kb, Vb, kD);
    attn_flash3<<<dim3(kB * kH, kN / 128), 512, 0, stream>>>(Qb, Kb, Vb,
                                                             bits_t, Hd);
    gtile3<128, 0, 0, 0><<<dim3(kR / 16, 1), 256, 0, stream>>>(
        Hd, wo_l, nullptr, nullptr, nullptr, x, h2, nullptr, nullptr, kD);
    gtile3<128, 1, 1, 0><<<dim3(kR / 16, kFF / 128), 256, 0, stream>>>(
        h2, enc_w1 + (size_t)l * kD * kFF, enc_ln2_g + l * kD,
        enc_ln2_b + l * kD, enc_b1 + l * kFF, nullptr, tb, nullptr, nullptr, kFF);
    float* xout = (l == kEnc - 1) ? out_enh : x;
    gtile3<512, 0, 0, 0><<<dim3(kR / 16, 1), 256, 0, stream>>>(
        tb, enc_w2 + (size_t)l * kFF * kD, nullptr, nullptr, enc_b2 + l * kD,
        h2, xout, nullptr, nullptr, kD);
  }

  // decoder (algebraic)
  dec_prep<<<kB, 256, 0, stream>>>(out_enh, target_index, current_index,
                                   center_index, dqkvW, dec_ln1_g, dec_ln1_b,
                                   dec_wk, out_curf, out_cenf, tgtf_ws, qk_ws);
  gtile3<128, 0, 0, 0><<<dim3(kB * kNC / 16, 1), 256, 0, stream>>>(
      out_cenf, ptr_wk, nullptr, nullptr, nullptr, nullptr, Kp_ws, nullptr,
      nullptr, kD);
  dec_score<<<dim3(kB, 16), 256, 0, stream>>>(out_enh, dec_ln1_g, dec_ln1_b,
                                              qk_ws, padbits, ln_ws, scores_ws);
  dec_softmax<<<kB, 256, 0, stream>>>(scores_ws, ml_ws);
  dec_attnsum<<<dim3(kB, 16), 256, 0, stream>>>(ln_ws, scores_ws, ml_ws,
                                                partial_ws);
  dec_tail<<<kB, 1024, 0, stream>>>(
      partial_ws, dec_wv, dec_wo, tgtf_ws, out_cenf, Kp_ws, center_index,
      center_mask, dec_ln2_g, dec_ln2_b, dec_w1, dec_b1, dec_w2, dec_b2,
      tgt_W, tgt_b, ptr_wq, out_selidx, out_selfeat, out_logp);
}

// Round 15
// 796.995 us; speedup vs baseline: 1.8589x; 1.8589x over previous
//
#include <hip/hip_runtime.h>

constexpr int kB = 4, kN = 1024, kIn = 8, kD = 128, kH = 8, kNC = 64,
              kDK = 16, kFF = 512, kEnc = 6, kR = kB * kN;

__device__ __forceinline__ float wredsum(float v) {
  v += __shfl_xor(v, 1);  v += __shfl_xor(v, 2);  v += __shfl_xor(v, 4);
  v += __shfl_xor(v, 8);  v += __shfl_xor(v, 16); v += __shfl_xor(v, 32);
  return v;
}
__device__ __forceinline__ float wredmax(float v) {
  v = fmaxf(v, __shfl_xor(v, 1));  v = fmaxf(v, __shfl_xor(v, 2));
  v = fmaxf(v, __shfl_xor(v, 4));  v = fmaxf(v, __shfl_xor(v, 8));
  v = fmaxf(v, __shfl_xor(v, 16)); v = fmaxf(v, __shfl_xor(v, 32));
  return v;
}
__device__ __forceinline__ float red4(float v) {
  v += __shfl_xor(v, 1);  v += __shfl_xor(v, 2);
  return v;
}

// ---- prologue kernels ----

__global__ __launch_bounds__(256) void repack_qkv(
    const float* __restrict__ wq, const float* __restrict__ wk,
    const float* __restrict__ wv, float* __restrict__ out, int layers) {
  int i = blockIdx.x * 256 + threadIdx.x;
  if (i >= layers * kD * kD) return;
  int l = i / (kD * kD);
  int rem = i - l * kD * kD;
  int d = rem >> 7;
  int c = rem & 127;
  int src = ((l * kH + (c >> 4)) * kD + d) * kDK + (c & 15);
  out[(size_t)(l * 3 + 0) * 16384 + rem] = wq[src];
  out[(size_t)(l * 3 + 1) * 16384 + rem] = wk[src];
  out[(size_t)(l * 3 + 2) * 16384 + rem] = wv[src];
}

__global__ __launch_bounds__(256) void pack_mask(
    const int* __restrict__ edge_mask, const int* __restrict__ pad_mask,
    unsigned long long* __restrict__ bits_t) {
  int row = blockIdx.x;  // b*N + q
  int b = row / kN;
  int q = row % kN;
  int lane = threadIdx.x & 63;
  int wv = threadIdx.x >> 6;
  for (int c0 = wv; c0 < 16; c0 += 4) {
    int k = c0 * 64 + lane;
    int m = edge_mask[(size_t)row * kN + k] + pad_mask[b * kN + k];
    unsigned long long bal = __ballot(m > 0);
    if (lane == 0) bits_t[((size_t)b * 16 + c0) * kN + q] = bal;
  }
}

__global__ __launch_bounds__(256) void pack_pad(
    const int* __restrict__ pad_mask, unsigned long long* __restrict__ bits) {
  int b = blockIdx.x;
  int lane = threadIdx.x & 63;
  int wv = threadIdx.x >> 6;
  for (int c0 = wv; c0 < 16; c0 += 4) {
    int k = c0 * 64 + lane;
    unsigned long long bal = __ballot(pad_mask[b * kN + k] > 0);
    if (lane == 0) bits[b * 16 + c0] = bal;
  }
}

__global__ __launch_bounds__(256) void init_proj(
    const float* __restrict__ ni, const float* __restrict__ W,
    const float* __restrict__ bias, float* __restrict__ x) {
  int i = blockIdx.x * 256 + threadIdx.x;  // r*128 + c
  int r = i >> 7, c = i & 127;
  float acc = bias[c];
#pragma unroll
  for (int k = 0; k < kIn; k++) acc = fmaf(ni[r * kIn + k], W[k * kD + c], acc);
  x[i] = acc;
}

// ---- gtile4: fp32 GEMM, 16 rows x 128 cols/block, 2 rows x 4 consecutive
// cols per thread. As padded +4 (conflict-free half-wave b128); Ws b128
// conflict-free; W streamed in 32-row double-buffered chunks (all K).
template <int K, int LN, int RELU, int MODE>
__global__ __launch_bounds__(256) void gtile4(
    const float* __restrict__ A, const float* __restrict__ Wg,
    const float* __restrict__ gamma, const float* __restrict__ beta,
    const float* __restrict__ bias, const float* __restrict__ resid,
    float* __restrict__ O0, float* __restrict__ O1, float* __restrict__ O2,
    int Cfull) {
  constexpr int NC = K / 32;
  __shared__ float As[16][K + 4];
  __shared__ float Ws[2][32][128];
  int r0 = blockIdx.x * 16;
  int y = blockIdx.y;
  const float* Wb;
  int wstride;
  if constexpr (MODE == 2) { Wb = Wg + (size_t)y * K * 128; wstride = 128; }
  else { Wb = Wg + (size_t)y * 128; wstride = Cfull; }

  // ---- stage A (opt fused LN) ----
  if constexpr (LN) {
    static_assert(K == 128, "LN requires K==128");
    int w = threadIdx.x >> 6, lane = threadIdx.x & 63;
#pragma unroll
    for (int i = 0; i < 4; i++) {
      int rr = w * 4 + i;
      const float* xr = A + (size_t)(r0 + rr) * 128;
      float2 v = *(const float2*)(xr + lane * 2);
      float mean = wredsum(v.x + v.y) * (1.0f / 128.f);
      float dx = v.x - mean, dy = v.y - mean;
      float var = wredsum(dx * dx + dy * dy) * (1.0f / 128.f);
      float rstd = rsqrtf(var + 1e-5f);
      int c = lane * 2;
      As[rr][c] = dx * rstd * gamma[c] + beta[c];
      As[rr][c + 1] = dy * rstd * gamma[c + 1] + beta[c + 1];
    }
  } else {
    constexpr int NF4 = K / 4;
    for (int f = threadIdx.x; f < 16 * NF4; f += 256) {
      int row = f / NF4, c4i = f % NF4;
      *(float4*)&As[row][c4i * 4] =
          *(const float4*)(A + (size_t)(r0 + row) * K + c4i * 4);
    }
  }

  // W staging: thread t -> rows (t>>5)+8j, cols (t&31)*4 (conflict-free)
  int wrow = threadIdx.x >> 5;
  int wc4 = threadIdx.x & 31;
  float4 wreg[4];
  auto loadW = [&](int kc) {
    const float* Wr = Wb + (size_t)(kc * 32 + wrow) * wstride + wc4 * 4;
#pragma unroll
    for (int j = 0; j < 4; j++)
      wreg[j] = *(const float4*)(Wr + (size_t)8 * j * wstride);
  };
  auto writeW = [&](int buf) {
#pragma unroll
    for (int j = 0; j < 4; j++)
      *(float4*)&Ws[buf][wrow + 8 * j][wc4 * 4] = wreg[j];
  };

  loadW(0);
  writeW(0);

  int c4 = (threadIdx.x & 31) * 4;   // 4 consecutive cols
  int rg = threadIdx.x >> 5;         // rows rg*2, rg*2+1
  float acc[2][4] = {};
  for (int kc = 0; kc < NC; kc++) {
    if (kc + 1 < NC) loadW(kc + 1);
    __syncthreads();
#pragma unroll
    for (int k4 = 0; k4 < 8; k4++) {
      float4 a0 = *(const float4*)&As[rg * 2][kc * 32 + k4 * 4];
      float4 a1 = *(const float4*)&As[rg * 2 + 1][kc * 32 + k4 * 4];
#pragma unroll
      for (int m = 0; m < 4; m++) {
        float4 wv = *(const float4*)&Ws[kc & 1][k4 * 4 + m][c4];
        float av0 = ((const float*)&a0)[m];
        float av1 = ((const float*)&a1)[m];
        acc[0][0] = fmaf(av0, wv.x, acc[0][0]);
        acc[0][1] = fmaf(av0, wv.y, acc[0][1]);
        acc[0][2] = fmaf(av0, wv.z, acc[0][2]);
        acc[0][3] = fmaf(av0, wv.w, acc[0][3]);
        acc[1][0] = fmaf(av1, wv.x, acc[1][0]);
        acc[1][1] = fmaf(av1, wv.y, acc[1][1]);
        acc[1][2] = fmaf(av1, wv.z, acc[1][2]);
        acc[1][3] = fmaf(av1, wv.w, acc[1][3]);
      }
    }
    if (kc + 1 < NC) writeW((kc + 1) & 1);
  }

  // ---- epilogue ----
#pragma unroll
  for (int rr = 0; rr < 2; rr++) {
    int r = r0 + rg * 2 + rr;
    if constexpr (MODE == 2) {
#pragma unroll
      for (int j = 0; j < 4; j++) {
        int c = c4 + j;
        float v = acc[rr][j];
        int hh = c >> 4, e = c & 15;
        int bb = r >> 10, n = r & 1023;
        float* P = (y == 0) ? O0 : (y == 1) ? O1 : O2;
        P[(((size_t)(bb * kH + hh)) * kN + n) * kDK + e] = v;
      }
    } else {
      int colg = y * 128 + c4;
      float4 v = make_float4(acc[rr][0], acc[rr][1], acc[rr][2], acc[rr][3]);
      if (bias) {
        float4 bv = *(const float4*)(bias + colg);
        v.x += bv.x; v.y += bv.y; v.z += bv.z; v.w += bv.w;
      }
      if (resid) {
        float4 rv = *(const float4*)(resid + (size_t)r * Cfull + colg);
        v.x += rv.x; v.y += rv.y; v.z += rv.z; v.w += rv.w;
      }
      if (RELU) {
        v.x = fmaxf(v.x, 0.f); v.y = fmaxf(v.y, 0.f);
        v.z = fmaxf(v.z, 0.f); v.w = fmaxf(v.w, 0.f);
      }
      *(float4*)(O0 + (size_t)r * Cfull + colg) = v;
    }
  }
}

// ---- flash attention v3: 128 q per block (2 per lane), 8 k-split waves ----
__global__ __launch_bounds__(512) void attn_flash3(
    const float* __restrict__ Q, const float* __restrict__ K,
    const float* __restrict__ V, const unsigned long long* __restrict__ bits_t,
    float* __restrict__ Hd) {
  __shared__ float Ks[8][64][20];
  __shared__ float Vs[8][64][20];
  int bh = blockIdx.x, qt = blockIdx.y;
  int b = bh >> 3, h = bh & 7;
  int w = threadIdx.x >> 6, lane = threadIdx.x & 63;
  int q0 = qt * 128 + lane, q1 = q0 + 64;
  const float4* qp0 = (const float4*)(Q + ((size_t)bh * kN + q0) * kDK);
  const float4* qp1 = (const float4*)(Q + ((size_t)bh * kN + q1) * kDK);
  float4 qa0 = qp0[0], qa1 = qp0[1], qa2 = qp0[2], qa3 = qp0[3];
  float4 qb0 = qp1[0], qb1 = qp1[1], qb2 = qp1[2], qb3 = qp1[3];
  const float* Kb = K + (size_t)bh * kN * kDK;
  const float* Vb = V + (size_t)bh * kN * kDK;
  float mx0 = -3.0e38f, l0 = 0.f, mx1 = -3.0e38f, l1 = 0.f;
  float acc0[16], acc1[16];
#pragma unroll
  for (int e = 0; e < 16; e++) { acc0[e] = 0.f; acc1[e] = 0.f; }
  for (int t = 0; t < 2; t++) {
    int kk = w * 128 + t * 64 + lane;
    const float4* kp = (const float4*)(Kb + (size_t)kk * kDK);
    float4 ka = kp[0], kb2 = kp[1], kc = kp[2], kd = kp[3];
    const float4* vp = (const float4*)(Vb + (size_t)kk * kDK);
    float4 va = vp[0], vb = vp[1], vc = vp[2], vd = vp[3];
    unsigned long long mb0 = bits_t[((size_t)b * 16 + w * 2 + t) * kN + q0];
    unsigned long long mb1 = bits_t[((size_t)b * 16 + w * 2 + t) * kN + q1];
    ((float4*)&Ks[w][lane][0])[0] = ka;  ((float4*)&Ks[w][lane][0])[1] = kb2;
    ((float4*)&Ks[w][lane][0])[2] = kc;  ((float4*)&Ks[w][lane][0])[3] = kd;
    ((float4*)&Vs[w][lane][0])[0] = va;  ((float4*)&Vs[w][lane][0])[1] = vb;
    ((float4*)&Vs[w][lane][0])[2] = vc;  ((float4*)&Vs[w][lane][0])[3] = vd;
#pragma unroll 2
    for (int k2 = 0; k2 < 64; k2++) {
      const float4* kr = (const float4*)&Ks[w][k2][0];
      float4 k0 = kr[0], k1 = kr[1], k2v = kr[2], k3 = kr[3];
      float s0 = qa0.x * k0.x + qa0.y * k0.y + qa0.z * k0.z + qa0.w * k0.w
               + qa1.x * k1.x + qa1.y * k1.y + qa1.z * k1.z + qa1.w * k1.w
               + qa2.x * k2v.x + qa2.y * k2v.y + qa2.z * k2v.z + qa2.w * k2v.w
               + qa3.x * k3.x + qa3.y * k3.y + qa3.z * k3.z + qa3.w * k3.w;
      float s1 = qb0.x * k0.x + qb0.y * k0.y + qb0.z * k0.z + qb0.w * k0.w
               + qb1.x * k1.x + qb1.y * k1.y + qb1.z * k1.z + qb1.w * k1.w
               + qb2.x * k2v.x + qb2.y * k2v.y + qb2.z * k2v.z + qb2.w * k2v.w
               + qb3.x * k3.x + qb3.y * k3.y + qb3.z * k3.z + qb3.w * k3.w;
      s0 *= 0.25f; s1 *= 0.25f;
      if ((mb0 >> k2) & 1ull) s0 = -1e8f;
      if ((mb1 >> k2) & 1ull) s1 = -1e8f;
      float d0 = s0 - mx0;
      if (d0 > 8.f) {
        float sc = __expf(-d0);
        l0 *= sc;
#pragma unroll
        for (int e = 0; e < 16; e++) acc0[e] *= sc;
        mx0 = s0; d0 = 0.f;
      }
      float p0 = __expf(d0);
      l0 += p0;
      float d1 = s1 - mx1;
      if (d1 > 8.f) {
        float sc = __expf(-d1);
        l1 *= sc;
#pragma unroll
        for (int e = 0; e < 16; e++) acc1[e] *= sc;
        mx1 = s1; d1 = 0.f;
      }
      float p1 = __expf(d1);
      l1 += p1;
      const float4* vr = (const float4*)&Vs[w][k2][0];
      float4 v0 = vr[0], v1 = vr[1], v2 = vr[2], v3 = vr[3];
      acc0[0] = fmaf(p0, v0.x, acc0[0]);   acc0[1] = fmaf(p0, v0.y, acc0[1]);
      acc0[2] = fmaf(p0, v0.z, acc0[2]);   acc0[3] = fmaf(p0, v0.w, acc0[3]);
      acc0[4] = fmaf(p0, v1.x, acc0[4]);   acc0[5] = fmaf(p0, v1.y, acc0[5]);
      acc0[6] = fmaf(p0, v1.z, acc0[6]);   acc0[7] = fmaf(p0, v1.w, acc0[7]);
      acc0[8] = fmaf(p0, v2.x, acc0[8]);   acc0[9] = fmaf(p0, v2.y, acc0[9]);
      acc0[10] = fmaf(p0, v2.z, acc0[10]); acc0[11] = fmaf(p0, v2.w, acc0[11]);
      acc0[12] = fmaf(p0, v3.x, acc0[12]); acc0[13] = fmaf(p0, v3.y, acc0[13]);
      acc0[14] = fmaf(p0, v3.z, acc0[14]); acc0[15] = fmaf(p0, v3.w, acc0[15]);
      acc1[0] = fmaf(p1, v0.x, acc1[0]);   acc1[1] = fmaf(p1, v0.y, acc1[1]);
      acc1[2] = fmaf(p1, v0.z, acc1[2]);   acc1[3] = fmaf(p1, v0.w, acc1[3]);
      acc1[4] = fmaf(p1, v1.x, acc1[4]);   acc1[5] = fmaf(p1, v1.y, acc1[5]);
      acc1[6] = fmaf(p1, v1.z, acc1[6]);   acc1[7] = fmaf(p1, v1.w, acc1[7]);
      acc1[8] = fmaf(p1, v2.x, acc1[8]);   acc1[9] = fmaf(p1, v2.y, acc1[9]);
      acc1[10] = fmaf(p1, v2.z, acc1[10]); acc1[11] = fmaf(p1, v2.w, acc1[11]);
      acc1[12] = fmaf(p1, v3.x, acc1[12]); acc1[13] = fmaf(p1, v3.y, acc1[13]);
      acc1[14] = fmaf(p1, v3.z, acc1[14]); acc1[15] = fmaf(p1, v3.w, acc1[15]);
    }
  }
  __syncthreads();
  float* M0 = &Ks[w][lane][0];
  float* M1 = &Vs[w][lane][0];
#pragma unroll
  for (int e = 0; e < 16; e++) { M0[e] = acc0[e]; M1[e] = acc1[e]; }
  M0[16] = mx0; M0[17] = l0;
  M1[16] = mx1; M1[17] = l1;
  __syncthreads();
#pragma unroll
  for (int half = 0; half < 2; half++) {
    const float* M = half ? &Vs[0][0][0] : &Ks[0][0][0];
    float mv[8];
#pragma unroll
    for (int p = 0; p < 8; p++) mv[p] = M[(p * 64 + lane) * 20 + 16];
    float mstar = mv[0];
#pragma unroll
    for (int p = 1; p < 8; p++) mstar = fmaxf(mstar, mv[p]);
    float f[8];
    float L = 0.f;
#pragma unroll
    for (int p = 0; p < 8; p++) {
      f[p] = __expf(mv[p] - mstar);
      L += f[p] * M[(p * 64 + lane) * 20 + 17];
    }
    float invL = 1.0f / L;
    float o[2];
#pragma unroll
    for (int e = 0; e < 2; e++) {
      int ei = w * 2 + e;
      float a = 0.f;
#pragma unroll
      for (int p = 0; p < 8; p++) a += f[p] * M[(p * 64 + lane) * 20 + ei];
      o[e] = a * invL;
    }
    int q = qt * 128 + half * 64 + lane;
    *(float2*)(Hd + ((size_t)(b * kN + q)) * kD + h * kDK + w * 2) =
        make_float2(o[0], o[1]);
  }
}

// ==== decoder (algebraic: K/V never materialized) ====

__global__ __launch_bounds__(256) void dec_prep(
    const float* __restrict__ enh, const int* __restrict__ tgt_idx,
    const int* __restrict__ cur_idx, const int* __restrict__ cen_idx,
    const float* __restrict__ Wq,
    const float* __restrict__ ln1_g, const float* __restrict__ ln1_b,
    const float* __restrict__ dec_wk,
    float* __restrict__ out_curf, float* __restrict__ out_cenf,
    float* __restrict__ tgtf_ws, float* __restrict__ qk_ws) {
  __shared__ float tgtf_s[128], tgtn[128], qd[128];
  int b = blockIdx.x, t = threadIdx.x;
  int lane = t & 63, w = t >> 6;
  int ti = tgt_idx[b], cui = cur_idx[b];
  if (t < 128) {
    float tf = enh[((size_t)b * kN + ti) * kD + t];
    tgtf_s[t] = tf;
    tgtf_ws[b * kD + t] = tf;
    out_curf[b * kD + t] = enh[((size_t)b * kN + cui) * kD + t];
  }
  for (int i = t; i < kNC * kD; i += 256) {
    int c = i >> 7, e = i & 127;
    out_cenf[((size_t)b * kNC + c) * kD + e] =
        enh[((size_t)b * kN + cen_idx[b * kNC + c]) * kD + e];
  }
  __syncthreads();
  if (w == 0) {
    float vx = tgtf_s[lane * 2], vy = tgtf_s[lane * 2 + 1];
    float mean = wredsum(vx + vy) * (1.0f / 128.f);
    float dx = vx - mean, dy = vy - mean;
    float var = wredsum(dx * dx + dy * dy) * (1.0f / 128.f);
    float rstd = rsqrtf(var + 1e-5f);
    tgtn[lane * 2] = dx * rstd * ln1_g[lane * 2] + ln1_b[lane * 2];
    tgtn[lane * 2 + 1] = dy * rstd * ln1_g[lane * 2 + 1] + ln1_b[lane * 2 + 1];
  }
  __syncthreads();
  if (t < 128) {
    float a = 0.f;
#pragma unroll 8
    for (int k = 0; k < 128; k++) a = fmaf(tgtn[k], Wq[k * 128 + t], a);
    qd[t] = a;
  }
  __syncthreads();
  int h = t >> 5, d0 = (t & 31) * 4;
#pragma unroll
  for (int j = 0; j < 4; j++) {
    int d = d0 + j;
    const float4* wp = (const float4*)(dec_wk + (((size_t)h * 128 + d) << 4));
    float a = 0.f;
#pragma unroll
    for (int r = 0; r < 4; r++) {
      float4 wv = wp[r];
      a += wv.x * qd[h * 16 + r * 4] + wv.y * qd[h * 16 + r * 4 + 1] +
           wv.z * qd[h * 16 + r * 4 + 2] + wv.w * qd[h * 16 + r * 4 + 3];
    }
    qk_ws[b * 1024 + h * 128 + d] = 0.25f * a;
  }
}

__global__ __launch_bounds__(256) void dec_score(
    const float* __restrict__ enh, const float* __restrict__ ln_g,
    const float* __restrict__ ln_b, const float* __restrict__ qk_ws,
    const unsigned long long* __restrict__ padbits,
    float* __restrict__ ln_ws, float* __restrict__ scores) {
  __shared__ float qs[8][128];
  int b = blockIdx.x, nt = blockIdx.y, t = threadIdx.x;
  for (int i = t; i < 1024; i += 256) ((float*)qs)[i] = qk_ws[b * 1024 + i];
  __syncthreads();
  int w = t >> 6, lane = t & 63, ri = lane >> 2, q4 = lane & 3;
  int n = nt * 64 + w * 16 + ri;
  const float* row = enh + ((size_t)b * kN + n) * kD;
  float4 xv[8];
#pragma unroll
  for (int j = 0; j < 8; j++) xv[j] = *(const float4*)(row + j * 16 + q4 * 4);
  float s1 = 0.f;
#pragma unroll
  for (int j = 0; j < 8; j++) s1 += xv[j].x + xv[j].y + xv[j].z + xv[j].w;
  s1 = red4(s1);
  float mean = s1 * (1.0f / 128.f);
  float s2 = 0.f;
#pragma unroll
  for (int j = 0; j < 8; j++) {
    xv[j].x -= mean; xv[j].y -= mean; xv[j].z -= mean; xv[j].w -= mean;
    s2 += xv[j].x * xv[j].x + xv[j].y * xv[j].y + xv[j].z * xv[j].z +
          xv[j].w * xv[j].w;
  }
  s2 = red4(s2);
  float rstd = rsqrtf(s2 * (1.0f / 128.f) + 1e-5f);
#pragma unroll
  for (int j = 0; j < 8; j++) {
    int d0 = j * 16 + q4 * 4;
    float4 g = *(const float4*)(ln_g + d0);
    float4 be = *(const float4*)(ln_b + d0);
    xv[j].x = xv[j].x * rstd * g.x + be.x;
    xv[j].y = xv[j].y * rstd * g.y + be.y;
    xv[j].z = xv[j].z * rstd * g.z + be.z;
    xv[j].w = xv[j].w * rstd * g.w + be.w;
    *(float4*)(ln_ws + ((size_t)b * kN + n) * kD + d0) = xv[j];
  }
  bool mk = (padbits[b * 16 + (n >> 6)] >> (n & 63)) & 1ull;
#pragma unroll
  for (int h = 0; h < 8; h++) {
    float p = 0.f;
#pragma unroll
    for (int j = 0; j < 8; j++) {
      float4 qv = *(const float4*)&qs[h][j * 16 + q4 * 4];
      p += xv[j].x * qv.x + xv[j].y * qv.y + xv[j].z * qv.z + xv[j].w * qv.w;
    }
    p = red4(p);
    if (q4 == 0) scores[((size_t)b * 8 + h) * 1024 + n] = mk ? -1e8f : p;
  }
}

__global__ __launch_bounds__(256) void dec_softmax(
    const float* __restrict__ scores, float* __restrict__ ml) {
  int b = blockIdx.x, t = threadIdx.x, w = t >> 6, lane = t & 63;
  for (int hi = 0; hi < 2; hi++) {
    int h = w + hi * 4;
    const float* sr = scores + ((size_t)b * 8 + h) * 1024;
    float v[16];
    float m = -3.0e38f;
#pragma unroll
    for (int i = 0; i < 16; i++) { v[i] = sr[i * 64 + lane]; m = fmaxf(m, v[i]); }
    m = wredmax(m);
    float l = 0.f;
#pragma unroll
    for (int i = 0; i < 16; i++) l += __expf(v[i] - m);
    l = wredsum(l);
    if (lane == 0) { ml[(b * 8 + h) * 2] = m; ml[(b * 8 + h) * 2 + 1] = l; }
  }
}

__global__ __launch_bounds__(256) void dec_attnsum(
    const float* __restrict__ ln_ws, const float* __restrict__ scores,
    const float* __restrict__ ml, float* __restrict__ partial) {
  __shared__ float lns[64][128];
  __shared__ float ps[8][64];
  int b = blockIdx.x, nt = blockIdx.y, t = threadIdx.x;
  for (int i = t; i < 64 * 32; i += 256) {
    int nn = i >> 5, c4 = i & 31;
    *(float4*)&lns[nn][c4 * 4] =
        *(const float4*)(ln_ws + ((size_t)b * kN + nt * 64 + nn) * kD + c4 * 4);
  }
  for (int i = t; i < 512; i += 256) {
    int h = i >> 6, nn = i & 63;
    float m = ml[(b * 8 + h) * 2], l = ml[(b * 8 + h) * 2 + 1];
    ps[h][nn] =
        __expf(scores[((size_t)b * 8 + h) * 1024 + nt * 64 + nn] - m) / l;
  }
  __syncthreads();
  int h = t >> 5, d0 = (t & 31) * 4;
  float4 acc = make_float4(0.f, 0.f, 0.f, 0.f);
  for (int nn = 0; nn < 64; nn++) {
    float p = ps[h][nn];
    float4 lv = *(const float4*)&lns[nn][d0];
    acc.x = fmaf(p, lv.x, acc.x); acc.y = fmaf(p, lv.y, acc.y);
    acc.z = fmaf(p, lv.z, acc.z); acc.w = fmaf(p, lv.w, acc.w);
  }
  *(float4*)(partial + ((size_t)(b * 16 + nt) * 8 + h) * 128 + d0) = acc;
}

// dec_tail: 1024 threads, parallel-k matvecs via LDS partial reduce
__global__ __launch_bounds__(1024) void dec_tail(
    const float* __restrict__ partial, const float* __restrict__ dec_wv,
    const float* __restrict__ dwo, const float* __restrict__ tgtf_ws,
    const float* __restrict__ cenf_g, const float* __restrict__ Kp,
    const int* __restrict__ cen_idx, const int* __restrict__ center_mask,
    const float* __restrict__ ln2_g, const float* __restrict__ ln2_b,
    const float* __restrict__ w1, const float* __restrict__ b1,
    const float* __restrict__ w2, const float* __restrict__ b2,
    const float* __restrict__ tgt_W, const float* __restrict__ tgt_b,
    const float* __restrict__ ptr_wq,
    float* __restrict__ out_selidx, float* __restrict__ out_selfeat,
    float* __restrict__ out_logp) {
  __shared__ float wsum[8][132];
  __shared__ float red[8][132];
  __shared__ float red2[2][520];
  __shared__ float red16[16][68];
  __shared__ float tgtf[128], hdd[128], dechs[128], decfs[128], dects[512],
                   embs[128], qps[128];
  __shared__ int bi_s;
  int b = blockIdx.x, t = threadIdx.x;
  int c = t & 127, p = t >> 7;
  int lane = t & 63, w = t >> 6;

  {
    float a = 0.f;
#pragma unroll
    for (int tt = 0; tt < 16; tt++)
      a += partial[((size_t)(b * 16 + tt) * 8 + p) * 128 + c];
    wsum[p][c] = a;
    if (t < 128) tgtf[t] = tgtf_ws[b * kD + t];
  }
  __syncthreads();

  {
    int h = c >> 4, e = c & 15;
    float a = 0.f;
#pragma unroll
    for (int i = 0; i < 16; i++) {
      int d = p * 16 + i;
      a = fmaf(wsum[h][d], dec_wv[((size_t)h * 128 + d) * 16 + e], a);
    }
    red[p][c] = a;
  }
  __syncthreads();
  if (t < 128) {
    float a = 0.f;
#pragma unroll
    for (int q = 0; q < 8; q++) a += red[q][t];
    hdd[t] = a;
  }
  __syncthreads();

  {
    float a = 0.f;
#pragma unroll
    for (int i = 0; i < 16; i++) {
      int k = p * 16 + i;
      a = fmaf(hdd[k], dwo[k * 128 + c], a);
    }
    red[p][c] = a;
  }
  __syncthreads();
  if (t < 128) {
    float a = 0.f;
#pragma unroll
    for (int q = 0; q < 8; q++) a += red[q][t];
    dechs[t] = a + tgtf[t];
  }
  __syncthreads();

  if (w == 0) {
    float vx = dechs[lane * 2], vy = dechs[lane * 2 + 1];
    float mean = wredsum(vx + vy) * (1.0f / 128.f);
    float dx = vx - mean, dy = vy - mean;
    float var = wredsum(dx * dx + dy * dy) * (1.0f / 128.f);
    float rstd = rsqrtf(var + 1e-5f);
    decfs[lane * 2] = dx * rstd * ln2_g[lane * 2] + ln2_b[lane * 2];
    decfs[lane * 2 + 1] = dy * rstd * ln2_g[lane * 2 + 1] + ln2_b[lane * 2 + 1];
  }
  __syncthreads();

  {
    int c5 = t & 511, p2 = t >> 9;
    float a = 0.f;
#pragma unroll 8
    for (int i = 0; i < 64; i++) {
      int k = p2 * 64 + i;
      a = fmaf(decfs[k], w1[k * 512 + c5], a);
    }
    red2[p2][c5] = a;
  }
  __syncthreads();
  if (t < 512) dects[t] = fmaxf(red2[0][t] + red2[1][t] + b1[t], 0.f);
  __syncthreads();

  {
    float a = 0.f;
#pragma unroll 8
    for (int i = 0; i < 64; i++) {
      int k = p * 64 + i;
      a = fmaf(dects[k], w2[k * 128 + c], a);
    }
    red[p][c] = a;
  }
  __syncthreads();
  if (t < 128) {
    float a = 0.f;
#pragma unroll
    for (int q = 0; q < 8; q++) a += red[q][t];
    decfs[t] = a + b2[t] + dechs[t];
  }
  __syncthreads();

  {
    float a = 0.f;
#pragma unroll
    for (int i = 0; i < 32; i++) {
      int k = p * 32 + i;
      float vkk = (k < 128) ? decfs[k] : tgtf[k - 128];
      a = fmaf(vkk, tgt_W[k * 128 + c], a);
    }
    red[p][c] = a;
  }
  __syncthreads();
  if (t < 128) {
    float a = 0.f;
#pragma unroll
    for (int q = 0; q < 8; q++) a += red[q][t];
    embs[t] = a + tgt_b[t];
  }
  __syncthreads();

  {
    float a = 0.f;
#pragma unroll
    for (int i = 0; i < 16; i++) {
      int k = p * 16 + i;
      a = fmaf(embs[k], ptr_wq[k * 128 + c], a);
    }
    red[p][c] = a;
  }
  __syncthreads();
  if (t < 128) {
    float a = 0.f;
#pragma unroll
    for (int q = 0; q < 8; q++) a += red[q][t];
    qps[t] = a;
  }
  __syncthreads();

  {
    int cen = t & 63, p16 = t >> 6;
    float a = 0.f;
#pragma unroll
    for (int i = 0; i < 8; i++) {
      int k = p16 * 8 + i;
      a = fmaf(qps[k], Kp[((size_t)(b * kNC + cen)) * kD + k], a);
    }
    red16[p16][cen] = a;
  }
  __syncthreads();
  if (w == 0) {
    float u = 0.f;
#pragma unroll
    for (int q = 0; q < 16; q++) u += red16[q][lane];
    u *= 0.08838834764831845f;
    u = 10.0f * tanhf(u);
    if (center_mask[b * kNC + lane] == 1) u = -1e8f;
    float m = wredmax(u);
    float ex = __expf(u - m);
    float sum = wredsum(ex);
    out_logp[b * kNC + lane] = u - m - logf(sum);
    float bm = u; int bi = lane;
#pragma unroll
    for (int o = 32; o; o >>= 1) {
      float om = __shfl_xor(bm, o);
      int oi = __shfl_xor(bi, o);
      if (om > bm || (om == bm && oi < bi)) { bm = om; bi = oi; }
    }
    if (lane == 0) {
      out_selidx[b] = (float)cen_idx[b * kNC + bi];
      bi_s = bi;
    }
  }
  __syncthreads();
  if (t < 128)
    out_selfeat[b * kD + t] = cenf_g[((size_t)(b * kNC + bi_s)) * kD + t];
}

// ---- host ----

extern "C" void kernel_launch(void* const* d_in, const int* in_sizes, int n_in,
                              void* d_out, int out_size, void* d_ws,
                              size_t ws_size, hipStream_t stream) {
  (void)in_sizes; (void)n_in; (void)out_size; (void)ws_size;
  const float* node_inputs = (const float*)d_in[0];
  const int* pad_mask = (const int*)d_in[1];
  const int* edge_mask = (const int*)d_in[2];
  const int* center_mask = (const int*)d_in[3];
  const int* center_index = (const int*)d_in[4];
  const int* target_index = (const int*)d_in[5];
  const int* current_index = (const int*)d_in[6];
  const float* init_W = (const float*)d_in[8];
  const float* init_b = (const float*)d_in[9];
  const float* enc_wq = (const float*)d_in[10];
  const float* enc_wk = (const float*)d_in[11];
  const float* enc_wv = (const float*)d_in[12];
  const float* enc_wo = (const float*)d_in[13];
  const float* enc_ln1_g = (const float*)d_in[14];
  const float* enc_ln1_b = (const float*)d_in[15];
  const float* enc_w1 = (const float*)d_in[16];
  const float* enc_b1 = (const float*)d_in[17];
  const float* enc_w2 = (const float*)d_in[18];
  const float* enc_b2 = (const float*)d_in[19];
  const float* enc_ln2_g = (const float*)d_in[20];
  const float* enc_ln2_b = (const float*)d_in[21];
  const float* dec_wq = (const float*)d_in[22];
  const float* dec_wk = (const float*)d_in[23];
  const float* dec_wv = (const float*)d_in[24];
  const float* dec_wo = (const float*)d_in[25];
  const float* dec_ln1_g = (const float*)d_in[26];
  const float* dec_ln1_b = (const float*)d_in[27];
  const float* dec_w1 = (const float*)d_in[28];
  const float* dec_b1 = (const float*)d_in[29];
  const float* dec_w2 = (const float*)d_in[30];
  const float* dec_b2 = (const float*)d_in[31];
  const float* dec_ln2_g = (const float*)d_in[32];
  const float* dec_ln2_b = (const float*)d_in[33];
  const float* tgt_W = (const float*)d_in[34];
  const float* tgt_b = (const float*)d_in[35];
  const float* ptr_wq = (const float*)d_in[36];
  const float* ptr_wk = (const float*)d_in[37];

  float* out_enh = (float*)d_out;
  float* out_curf = out_enh + kB * kN * kD;
  float* out_selidx = out_curf + kB * kD;
  float* out_selfeat = out_selidx + kB;
  float* out_logp = out_selfeat + kB * kD;
  float* out_cenf = out_logp + kB * kNC;

  char* wsp = (char*)d_ws;
  size_t off = 0;
  auto alloc = [&](size_t n) {
    char* p = wsp + off;
    off = (off + n + 255) & ~(size_t)255;
    return p;
  };
  float* x   = (float*)alloc(kR * kD * 4);
  float* h2  = (float*)alloc(kR * kD * 4);
  float* Qb  = (float*)alloc(kR * kD * 4);
  float* Kb  = (float*)alloc(kR * kD * 4);
  float* Vb  = (float*)alloc(kR * kD * 4);
  float* Hd  = (float*)alloc(kR * kD * 4);
  float* tb  = (float*)alloc(kR * kFF * 4);
  unsigned long long* bits_t  = (unsigned long long*)alloc(kR * 16 * 8);
  unsigned long long* padbits = (unsigned long long*)alloc(kB * 16 * 8);
  float* ewqkv = (float*)alloc(kEnc * 3 * kD * kD * 4);
  float* dqkvW = (float*)alloc(3 * kD * kD * 4);
  float* ln_ws = (float*)alloc(kR * kD * 4);
  float* scores_ws = (float*)alloc(kB * kH * kN * 4);
  float* ml_ws = (float*)alloc(kB * kH * 2 * 4);
  float* partial_ws = (float*)alloc(kB * 16 * kH * kD * 4);
  float* qk_ws = (float*)alloc(kB * kH * kD * 4);
  float* tgtf_ws = (float*)alloc(kB * kD * 4);
  float* Kp_ws = (float*)alloc(kB * kNC * kD * 4);

  // prologue
  repack_qkv<<<(kEnc * kD * kD + 255) / 256, 256, 0, stream>>>(
      enc_wq, enc_wk, enc_wv, ewqkv, kEnc);
  repack_qkv<<<(kD * kD + 255) / 256, 256, 0, stream>>>(
      dec_wq, dec_wk, dec_wv, dqkvW, 1);
  pack_mask<<<kB * kN, 256, 0, stream>>>(edge_mask, pad_mask, bits_t);
  pack_pad<<<kB, 256, 0, stream>>>(pad_mask, padbits);
  init_proj<<<kR * kD / 256, 256, 0, stream>>>(node_inputs, init_W, init_b, x);

  // encoder
  for (int l = 0; l < kEnc; l++) {
    const float* wo_l = enc_wo + (size_t)l * kH * kDK * kD;
    gtile4<128, 1, 0, 2><<<dim3(kR / 16, 3), 256, 0, stream>>>(
        x, ewqkv + (size_t)l * 3 * kD * kD, enc_ln1_g + l * kD,
        enc_ln1_b + l * kD, nullptr, nullptr, Qb, Kb, Vb, kD);
    attn_flash3<<<dim3(kB * kH, kN / 128), 512, 0, stream>>>(Qb, Kb, Vb,
                                                             bits_t, Hd);
    gtile4<128, 0, 0, 0><<<dim3(kR / 16, 1), 256, 0, stream>>>(
        Hd, wo_l, nullptr, nullptr, nullptr, x, h2, nullptr, nullptr, kD);
    gtile4<128, 1, 1, 0><<<dim3(kR / 16, kFF / 128), 256, 0, stream>>>(
        h2, enc_w1 + (size_t)l * kD * kFF, enc_ln2_g + l * kD,
        enc_ln2_b + l * kD, enc_b1 + l * kFF, nullptr, tb, nullptr, nullptr, kFF);
    float* xout = (l == kEnc - 1) ? out_enh : x;
    gtile4<512, 0, 0, 0><<<dim3(kR / 16, 1), 256, 0, stream>>>(
        tb, enc_w2 + (size_t)l * kFF * kD, nullptr, nullptr, enc_b2 + l * kD,
        h2, xout, nullptr, nullptr, kD);
  }

  // decoder (algebraic)
  dec_prep<<<kB, 256, 0, stream>>>(out_enh, target_index, current_index,
                                   center_index, dqkvW, dec_ln1_g, dec_ln1_b,
                                   dec_wk, out_curf, out_cenf, tgtf_ws, qk_ws);
  gtile4<128, 0, 0, 0><<<dim3(kB * kNC / 16, 1), 256, 0, stream>>>(
      out_cenf, ptr_wk, nullptr, nullptr, nullptr, nullptr, Kp_ws, nullptr,
      nullptr, kD);
  dec_score<<<dim3(kB, 16), 256, 0, stream>>>(out_enh, dec_ln1_g, dec_ln1_b,
                                              qk_ws, padbits, ln_ws, scores_ws);
  dec_softmax<<<kB, 256, 0, stream>>>(scores_ws, ml_ws);
  dec_attnsum<<<dim3(kB, 16), 256, 0, stream>>>(ln_ws, scores_ws, ml_ws,
                                                partial_ws);
  dec_tail<<<kB, 1024, 0, stream>>>(
      partial_ws, dec_wv, dec_wo, tgtf_ws, out_cenf, Kp_ws, center_index,
      center_mask, dec_ln2_g, dec_ln2_b, dec_w1, dec_b1, dec_w2, dec_b2,
      tgt_W, tgt_b, ptr_wq, out_selidx, out_selfeat, out_logp);
}